// Round 12
// baseline (73.859 us; speedup 1.0000x reference)
//
#include <hip/hip_runtime.h>

#define NGT 30000
#define GT_TILE 512
#define NBLK_G 59            // ceil(30000/512)
#define PRANGE 128           // preds per block
#define NCHUNK 27            // m0: 2, m1: 5, m2: 20 chunks of 128
#define NPACK 3456           // 27 * 128 chunk-padded pred slots
#define RB 128               // reduce blocks

typedef float v2f __attribute__((ext_vector_type(2)));

// ws layout (float offsets). predpack first (16B aligned at ws base).
#define OFF_PREDPACK 0              // 3456 float4 = 13824 floats
#define OFF_GTPART   13824          // 27 * 30000 = 810000 (16B-aligned: 13824*4B)
#define OFF_PREDMIN  823824         // 3240
#define OFF_PARTIALS 827064         // RB*4 = 512
#define OFF_COUNTER  827576         // 1 uint

// ---------------------------------------------------------------------------
// Pack kernel: predpack[i] = {x,y,z,norm} (sentinel w=3e38 for pad slots);
// also inits predmin[3240] and zeroes the done-counter (no memset dispatch).
// Layout: m0 slots [0,256), m1 [256,896), m2 [896,3456).
// ---------------------------------------------------------------------------
__global__ __launch_bounds__(256) void pack_kernel(
    const float* __restrict__ pbd0,
    const float* __restrict__ pbd1,
    const float* __restrict__ pbd2,
    float4* __restrict__ predpack,
    float* __restrict__ predmin,
    unsigned* __restrict__ counter)
{
    const int i = blockIdx.x * 256 + threadIdx.x;
    if (i == 0) *counter = 0u;
    if (i < 3240) predmin[i] = __int_as_float(0x7f7f7f7f);
    if (i >= NPACK) return;
    int mesh, j, n;
    if (i < 256)      { mesh = 0; j = i;       n = 156; }
    else if (i < 896) { mesh = 1; j = i - 256; n = 618; }
    else              { mesh = 2; j = i - 896; n = 2466; }
    const float* p = (mesh == 0) ? pbd0 : (mesh == 1) ? pbd1 : pbd2;
    float4 v = make_float4(0.f, 0.f, 0.f, 3.0e38f);
    if (j < n) {
        float x = p[3*j], y = p[3*j+1], z = p[3*j+2];
        v = make_float4(x, y, z, x*x + y*y + z*z);
    }
    predpack[i] = v;
}

// ---------------------------------------------------------------------------
// Two-phase chamfer, grid 59x27=1593 blocks (TLP is king — R9 lesson),
// packed f32 math (v_pk_fma), phase-2 LDS reads halved (R12).
// Phase 1: 2 gt pts/thread as v2f; preds via wave-uniform s_load_dwordx4
//          from predpack; ~3 VALU/pair; plain store to gtpart[c][g].
// Phase 2: 8-lane groups own 8 preds (component-packed v2f); 16 pred-sets
//          x 2 gt-halves = 32 groups; each group scans 256 gt rows in 32
//          ds_read_b128 (8 distinct addrs/wave + in-group broadcast ->
//          conflict-free); halves combine via atomicMin; 3-level shfl_xor
//          within the group -> atomicMin predmin (int bits, non-negative,
//          order-independent, deterministic).
// ---------------------------------------------------------------------------
__global__ __launch_bounds__(256) void chamfer_kernel(
    const float* __restrict__ gt,
    const float4* __restrict__ predpack,
    float* __restrict__ gtpart,    // [NCHUNK * NGT], write-only
    float* __restrict__ predmin)   // [3240], pre-init by pack_kernel
{
    __shared__ float4 sgt[GT_TILE];
    __shared__ float4 spred[PRANGE];

    const int tid = threadIdx.x;
    const int c = blockIdx.y;

    int mesh, cidx;
    if (c < 2)      { mesh = 0; cidx = c; }
    else if (c < 7) { mesh = 1; cidx = c - 2; }
    else            { mesh = 2; cidx = c - 7; }
    const int coff = cidx * PRANGE;
    const int n    = (mesh == 0) ? 156 : (mesh == 1) ? 618 : 2466;
    const int poff = (mesh == 0) ? 0   : (mesh == 1) ? 156 : 774;
    const int pbase = ((mesh == 0) ? 0 : (mesh == 1) ? 256 : 896) + coff;
    const int np = min(PRANGE, n - coff);

    if (tid < PRANGE) spred[tid] = predpack[pbase + tid];

    const int gbase = blockIdx.x * GT_TILE;
    float gx[2], gy[2], gz[2], g2[2];
    #pragma unroll
    for (int k = 0; k < 2; ++k) {
        const int g = gbase + k * 256 + tid;
        float x = 1e18f, y = 1e18f, z = 1e18f;   // sentinel gt: huge, finite
        if (g < NGT) { x = gt[3*g]; y = gt[3*g+1]; z = gt[3*g+2]; }
        gx[k] = x; gy[k] = y; gz[k] = z;
        g2[k] = x*x + y*y + z*z;
        sgt[k * 256 + tid] = make_float4(x, y, z, g2[k]);
    }
    __syncthreads();

    // ---- phase 1: gt-side min; scalar pred loads + packed f32 math ----
    {
        v2f gxv = {gx[0], gx[1]};
        v2f gyv = {gy[0], gy[1]};
        v2f gzv = {gz[0], gz[1]};
        v2f gminv = {3.0e38f, 3.0e38f};
        const float4* __restrict__ pp = predpack + pbase;  // uniform base
        #pragma unroll 8
        for (int j = 0; j < PRANGE; ++j) {
            const float4 p = pp[j];              // uniform -> SMEM load
            v2f dot = gxv * p.x;
            dot += gyv * p.y;                    // v_pk_fma
            dot += gzv * p.z;
            v2f t = dot * -2.0f + p.w;           // p2 - 2*dot (packed fma)
            gminv.x = fminf(gminv.x, t.x);
            gminv.y = fminf(gminv.y, t.y);
        }
        const float gm0 = gminv.x + g2[0];
        const float gm1 = gminv.y + g2[1];
        int g = gbase + tid;
        if (g < NGT)       gtpart[c * NGT + g] = gm0;
        g += 256;
        if (g < NGT)       gtpart[c * NGT + g] = gm1;
    }

    // ---- phase 2: 8-lane groups x 8 preds, half-tile scan, packed f32 ----
    {
        const int grp  = tid >> 3;                 // 0..31
        const int s    = tid & 7;                  // interleaved slice
        const int pset = (grp & 15) * 8;           // pred set base (16 sets)
        const int half = (grp >> 4) * 256;         // gt half base
        const float4 P0 = spred[pset+0], P1 = spred[pset+1];
        const float4 P2 = spred[pset+2], P3 = spred[pset+3];
        const float4 P4 = spred[pset+4], P5 = spred[pset+5];
        const float4 P6 = spred[pset+6], P7 = spred[pset+7];
        v2f px01 = {P0.x, P1.x}, px23 = {P2.x, P3.x};
        v2f px45 = {P4.x, P5.x}, px67 = {P6.x, P7.x};
        v2f py01 = {P0.y, P1.y}, py23 = {P2.y, P3.y};
        v2f py45 = {P4.y, P5.y}, py67 = {P6.y, P7.y};
        v2f pz01 = {P0.z, P1.z}, pz23 = {P2.z, P3.z};
        v2f pz45 = {P4.z, P5.z}, pz67 = {P6.z, P7.z};
        v2f mn01 = {3.0e38f, 3.0e38f}, mn23 = {3.0e38f, 3.0e38f};
        v2f mn45 = {3.0e38f, 3.0e38f}, mn67 = {3.0e38f, 3.0e38f};
        #pragma unroll 4
        for (int k = 0; k < 256 / 8; ++k) {
            const float4 q = sgt[half + k * 8 + s];  // conflict-free
            v2f d01 = px01 * q.x; d01 += py01 * q.y; d01 += pz01 * q.z;
            v2f d23 = px23 * q.x; d23 += py23 * q.y; d23 += pz23 * q.z;
            v2f d45 = px45 * q.x; d45 += py45 * q.y; d45 += pz45 * q.z;
            v2f d67 = px67 * q.x; d67 += py67 * q.y; d67 += pz67 * q.z;
            v2f t01 = d01 * -2.0f + q.w;             // g2 - 2*dot
            v2f t23 = d23 * -2.0f + q.w;
            v2f t45 = d45 * -2.0f + q.w;
            v2f t67 = d67 * -2.0f + q.w;
            mn01.x = fminf(mn01.x, t01.x); mn01.y = fminf(mn01.y, t01.y);
            mn23.x = fminf(mn23.x, t23.x); mn23.y = fminf(mn23.y, t23.y);
            mn45.x = fminf(mn45.x, t45.x); mn45.y = fminf(mn45.y, t45.y);
            mn67.x = fminf(mn67.x, t67.x); mn67.y = fminf(mn67.y, t67.y);
        }
        float mn[8] = {mn01.x, mn01.y, mn23.x, mn23.y,
                       mn45.x, mn45.y, mn67.x, mn67.y};
        float pw[8] = {P0.w, P1.w, P2.w, P3.w, P4.w, P5.w, P6.w, P7.w};
        #pragma unroll
        for (int off = 1; off < 8; off <<= 1) {
            #pragma unroll
            for (int r = 0; r < 8; ++r)
                mn[r] = fminf(mn[r], __shfl_xor(mn[r], off, 64));
        }
        if (s == 0) {
            #pragma unroll
            for (int r = 0; r < 8; ++r) {
                const int pj = pset + r;
                if (pj < np)
                    atomicMin((int*)(predmin + poff + coff + pj),
                              __float_as_int(mn[r] + pw[r]));
            }
        }
    }
}

// ---------------------------------------------------------------------------
// Partial reduce + fused final (last-block pattern).
// Index space: [0,7500) gt float4 min-combine over 27 gtpart slices |
// [7500,10740) predmin | [10740,20442) edges | [20442,23682) laplace.
// Last block sums the 128 partials in fixed tree order -> deterministic.
// ---------------------------------------------------------------------------
__global__ __launch_bounds__(256) void partial_kernel(
    const float* __restrict__ pc0, const float* __restrict__ pc1, const float* __restrict__ pc2,
    const float* __restrict__ pbd0, const float* __restrict__ pbd1, const float* __restrict__ pbd2,
    const int* __restrict__ ed0, const int* __restrict__ ed1, const int* __restrict__ ed2,
    const int* __restrict__ li0, const int* __restrict__ li1, const int* __restrict__ li2,
    const float* __restrict__ gtpart, const float* __restrict__ predmin,
    float* __restrict__ partials, unsigned* __restrict__ counter,
    float* __restrict__ out)
{
    const int   NVs[3]   = {156, 618, 2466};
    const int   NEs[3]   = {462, 1848, 7392};
    const int   poffs[3] = {0, 156, 774};
    const int   eoffs[3] = {0, 462, 2310};
    const float lapc[3]  = {0.2f, 1.0f, 1.0f};
    const float* pcs[3]  = {pc0, pc1, pc2};
    const float* pbds[3] = {pbd0, pbd1, pbd2};
    const int*   eds[3]  = {ed0, ed1, ed2};
    const int*   lis[3]  = {li0, li1, li2};

    const int tid = threadIdx.x;
    const int stride = gridDim.x * 256;
    float ch = 0.f, ed = 0.f, lp = 0.f;

    for (int idx = blockIdx.x * 256 + tid; idx < 23682; idx += stride) {
        if (idx < 7500) {
            // 4 gt points per item, float4 loads (all offsets 16B-aligned)
            const float4* gp = (const float4*)gtpart;   // [cc*7500 + idx]
            float4 a = gp[0 * 7500 + idx];
            float4 b = gp[1 * 7500 + idx];
            float4 m0 = make_float4(fminf(a.x,b.x), fminf(a.y,b.y),
                                    fminf(a.z,b.z), fminf(a.w,b.w));
            float4 m1 = make_float4(3.0e38f, 3.0e38f, 3.0e38f, 3.0e38f);
            #pragma unroll
            for (int cc = 2; cc < 7; ++cc) {
                float4 q = gp[cc * 7500 + idx];
                m1.x = fminf(m1.x, q.x); m1.y = fminf(m1.y, q.y);
                m1.z = fminf(m1.z, q.z); m1.w = fminf(m1.w, q.w);
            }
            float4 m2 = make_float4(3.0e38f, 3.0e38f, 3.0e38f, 3.0e38f);
            #pragma unroll
            for (int cc = 7; cc < 27; ++cc) {
                float4 q = gp[cc * 7500 + idx];
                m2.x = fminf(m2.x, q.x); m2.y = fminf(m2.y, q.y);
                m2.z = fminf(m2.z, q.z); m2.w = fminf(m2.w, q.w);
            }
            float s0 = (m0.x + m1.x + m2.x) + (m0.y + m1.y + m2.y);
            float s1 = (m0.z + m1.z + m2.z) + (m0.w + m1.w + m2.w);
            ch += (s0 + s1) * (1.0f / 30000.0f);
        } else if (idx < 10740) {
            int p = idx - 7500;
            int m = (p < 156) ? 0 : (p < 774) ? 1 : 2;
            ch += predmin[p] * (1.0f / (float)NVs[m]);
        } else if (idx < 20442) {
            int e = idx - 10740;
            int m = (e < 462) ? 0 : (e < 2310) ? 1 : 2;
            int el = e - eoffs[m];
            const int* E = eds[m];
            const float* P = pcs[m];
            int a = E[2*el], b = E[2*el+1];
            float dx = P[3*a]   - P[3*b];
            float dy = P[3*a+1] - P[3*b+1];
            float dz = P[3*a+2] - P[3*b+2];
            ed += (dx*dx + dy*dy + dz*dz) * (300.0f / (float)NEs[m]);
        } else {
            int v = idx - 20442;
            int m = (v < 156) ? 0 : (v < 774) ? 1 : 2;
            int vl = v - poffs[m];
            const int* L = lis[m];
            const float* PB = pbds[m];
            const float* PC = pcs[m];
            float mvx = PB[3*vl]   - PC[3*vl];
            float mvy = PB[3*vl+1] - PC[3*vl+1];
            float mvz = PB[3*vl+2] - PC[3*vl+2];
            float sx = 0.f, sy = 0.f, sz = 0.f;
            #pragma unroll
            for (int k = 0; k < 8; ++k) {
                int nb = L[10*vl + k];
                if (nb >= 0) {
                    sx += PB[3*nb]   - PC[3*nb];
                    sy += PB[3*nb+1] - PC[3*nb+1];
                    sz += PB[3*nb+2] - PC[3*nb+2];
                }
            }
            float invdeg = 1.0f / (float)L[10*vl + 9];
            float dx = mvx - sx * invdeg;
            float dy = mvy - sy * invdeg;
            float dz = mvz - sz * invdeg;
            float t = dx*dx + dy*dy + dz*dz;
            if (m > 0) t += mvx*mvx + mvy*mvy + mvz*mvz;
            lp += t * (lapc[m] / (float)NVs[m]);
        }
    }

    __shared__ float sred[12];
    __shared__ int is_last;
    for (int off = 32; off; off >>= 1) {
        ch += __shfl_down(ch, off, 64);
        ed += __shfl_down(ed, off, 64);
        lp += __shfl_down(lp, off, 64);
    }
    const int lane = tid & 63, wid = tid >> 6;
    if (lane == 0) { sred[wid] = ch; sred[4 + wid] = ed; sred[8 + wid] = lp; }
    __syncthreads();
    if (tid == 0) {
        partials[blockIdx.x * 4 + 0] = sred[0] + sred[1] + sred[2] + sred[3];
        partials[blockIdx.x * 4 + 1] = sred[4] + sred[5] + sred[6] + sred[7];
        partials[blockIdx.x * 4 + 2] = sred[8] + sred[9] + sred[10] + sred[11];
        __threadfence();
        unsigned prev = atomicAdd(counter, 1u);
        is_last = (prev == (unsigned)(gridDim.x - 1)) ? 1 : 0;
    }
    __syncthreads();

    if (is_last) {
        __threadfence();
        float c2 = 0.f, e2 = 0.f, l2 = 0.f;
        if (tid < RB) {
            c2 = partials[4*tid]; e2 = partials[4*tid+1]; l2 = partials[4*tid+2];
        }
        for (int off = 32; off; off >>= 1) {
            c2 += __shfl_down(c2, off, 64);
            e2 += __shfl_down(e2, off, 64);
            l2 += __shfl_down(l2, off, 64);
        }
        __shared__ float s2[12];
        if (lane == 0) { s2[wid] = c2; s2[4 + wid] = e2; s2[8 + wid] = l2; }
        __syncthreads();
        if (tid == 0) {
            float C = s2[0] + s2[1];       // wids 2,3 contributed zeros
            float E = s2[4] + s2[5];
            float L = s2[8] + s2[9];
            out[0] = 100.0f * C + 0.1f * E + 0.3f * L;
            out[1] = C;
            out[2] = E;
            out[3] = L;
        }
    }
}

extern "C" void kernel_launch(void* const* d_in, const int* in_sizes, int n_in,
                              void* d_out, int out_size, void* d_ws, size_t ws_size,
                              hipStream_t stream) {
    const float* gt   = (const float*)d_in[0];
    const float* pc0  = (const float*)d_in[1];
    const float* pbd0 = (const float*)d_in[2];
    const int*   ed0  = (const int*)  d_in[3];
    const int*   li0  = (const int*)  d_in[4];
    const float* pc1  = (const float*)d_in[5];
    const float* pbd1 = (const float*)d_in[6];
    const int*   ed1  = (const int*)  d_in[7];
    const int*   li1  = (const int*)  d_in[8];
    const float* pc2  = (const float*)d_in[9];
    const float* pbd2 = (const float*)d_in[10];
    const int*   ed2  = (const int*)  d_in[11];
    const int*   li2  = (const int*)  d_in[12];

    float* ws        = (float*)d_ws;
    float4* predpack = (float4*)(ws + OFF_PREDPACK);
    float* gtpart    = ws + OFF_GTPART;
    float* predmin   = ws + OFF_PREDMIN;
    float* partials  = ws + OFF_PARTIALS;
    unsigned* counter = (unsigned*)(ws + OFF_COUNTER);
    float* out       = (float*)d_out;

    pack_kernel<<<(NPACK + 255) / 256, 256, 0, stream>>>(
        pbd0, pbd1, pbd2, predpack, predmin, counter);

    dim3 grid(NBLK_G, NCHUNK);
    chamfer_kernel<<<grid, 256, 0, stream>>>(gt, predpack, gtpart, predmin);

    partial_kernel<<<RB, 256, 0, stream>>>(pc0, pc1, pc2, pbd0, pbd1, pbd2,
                                           ed0, ed1, ed2, li0, li1, li2,
                                           gtpart, predmin, partials, counter, out);
}

// Round 13
// 69.263 us; speedup vs baseline: 1.0664x; 1.0664x over previous
//
#include <hip/hip_runtime.h>

#define NGT 30000
#define GT_TILE 512
#define NBLK_G 59            // ceil(30000/512)
#define PRANGE 128           // preds per block
#define NCHUNK 27            // m0: 2, m1: 5, m2: 20 chunks of 128
#define NPACK 3456           // 27 * 128 chunk-padded pred slots
#define NGTPAD 30208         // 59 * 512 padded gt slots
#define RB 128               // reduce blocks

typedef float v2f __attribute__((ext_vector_type(2)));

// ws layout (float offsets); ws base is 16B-aligned.
#define OFF_GTPACK   0              // 30208 float4 = 120832 floats
#define OFF_PREDPACK 120832         // 3456 float4 = 13824 floats
#define OFF_GTPART   134656         // 27 * 30000 = 810000
#define OFF_PREDMIN  944656         // 3240
#define OFF_PARTIALS 947896         // RB*4 = 512
#define OFF_COUNTER  948408         // 1 uint

// ---------------------------------------------------------------------------
// Pack kernel: gtpack[i]={x,y,z,|g|^2} (pad slots w=3e38), predpack likewise
// (pad w=3e38); inits predmin and zeroes the done-counter (no memset).
// predpack layout: m0 [0,256), m1 [256,896), m2 [896,3456).
// ---------------------------------------------------------------------------
__global__ __launch_bounds__(256) void pack_kernel(
    const float* __restrict__ gt,
    const float* __restrict__ pbd0,
    const float* __restrict__ pbd1,
    const float* __restrict__ pbd2,
    float4* __restrict__ gtpack,
    float4* __restrict__ predpack,
    float* __restrict__ predmin,
    unsigned* __restrict__ counter)
{
    const int i = blockIdx.x * 256 + threadIdx.x;
    if (i == 0) *counter = 0u;
    if (i < 3240) predmin[i] = __int_as_float(0x7f7f7f7f);
    if (i < NGTPAD) {
        float4 v = make_float4(0.f, 0.f, 0.f, 3.0e38f);   // sentinel gt
        if (i < NGT) {
            float x = gt[3*i], y = gt[3*i+1], z = gt[3*i+2];
            v = make_float4(x, y, z, x*x + y*y + z*z);
        }
        gtpack[i] = v;
    } else if (i < NGTPAD + NPACK) {
        const int p = i - NGTPAD;
        int mesh, j, n;
        if (p < 256)      { mesh = 0; j = p;       n = 156; }
        else if (p < 896) { mesh = 1; j = p - 256; n = 618; }
        else              { mesh = 2; j = p - 896; n = 2466; }
        const float* pb = (mesh == 0) ? pbd0 : (mesh == 1) ? pbd1 : pbd2;
        float4 v = make_float4(0.f, 0.f, 0.f, 3.0e38f);   // sentinel pred
        if (j < n) {
            float x = pb[3*j], y = pb[3*j+1], z = pb[3*j+2];
            v = make_float4(x, y, z, x*x + y*y + z*z);
        }
        predpack[p] = v;
    }
}

// ---------------------------------------------------------------------------
// LDS-free two-phase chamfer. grid = (59, 27), block = 256. No LDS, no
// barriers (R11 post-mortem: ~24us/CU of ds_write+ds_read pipe time was the
// floor; R12 post-mortem: wide per-lane pred state trips the allocator).
// Both phases use wave-uniform s_load_dwordx4 + packed v2f (~3 VALU/pair).
// Phase 1: 2 gt/thread (float4 loads from gtpack); scan 128 preds via
//          s_load from predpack; store chunk-min to gtpart[c][g].
// Phase 2: lane owns preds {2*lane, 2*lane+1} (v2f, 8 VGPRs); wave wid
//          scans gt quarter [gbase+wid*128, +128) via s_load from gtpack;
//          guarded atomicMin into predmin (int bits of non-negative floats:
//          exact, order-independent, deterministic; init 0x7f7f7f7f).
// Sentinel slots carry w=3e38 so they never win a min.
// ---------------------------------------------------------------------------
__global__ __launch_bounds__(256) void chamfer_kernel(
    const float4* __restrict__ gtpack,
    const float4* __restrict__ predpack,
    float* __restrict__ gtpart,    // [NCHUNK * NGT], write-only
    float* __restrict__ predmin)   // [3240], pre-init by pack_kernel
{
    const int tid = threadIdx.x;
    const int c = blockIdx.y;

    int mesh, cidx;
    if (c < 2)      { mesh = 0; cidx = c; }
    else if (c < 7) { mesh = 1; cidx = c - 2; }
    else            { mesh = 2; cidx = c - 7; }
    const int coff = cidx * PRANGE;
    const int n    = (mesh == 0) ? 156 : (mesh == 1) ? 618 : 2466;
    const int poff = (mesh == 0) ? 0   : (mesh == 1) ? 156 : 774;
    const int pbase = ((mesh == 0) ? 0 : (mesh == 1) ? 256 : 896) + coff;
    const int np = min(PRANGE, n - coff);

    const int gbase = blockIdx.x * GT_TILE;
    const float4* __restrict__ pp = predpack + pbase;    // wave-uniform base

    // ---- phase 1: gt-side min; 2 gt/thread, preds via s_load ----
    {
        const float4 G0 = gtpack[gbase + tid];
        const float4 G1 = gtpack[gbase + 256 + tid];
        v2f gxv = {G0.x, G1.x};
        v2f gyv = {G0.y, G1.y};
        v2f gzv = {G0.z, G1.z};
        v2f gmin = {3.0e38f, 3.0e38f};
        #pragma unroll 8
        for (int j = 0; j < PRANGE; ++j) {
            const float4 p = pp[j];              // uniform -> s_load_dwordx4
            v2f dot = gxv * p.x;
            dot += gyv * p.y;                    // v_pk_fma
            dot += gzv * p.z;
            v2f t = dot * -2.0f + p.w;           // p2 - 2*dot
            gmin.x = fminf(gmin.x, t.x);
            gmin.y = fminf(gmin.y, t.y);
        }
        int g = gbase + tid;
        if (g < NGT)  gtpart[c * NGT + g] = gmin.x + G0.w;
        g += 256;
        if (g < NGT)  gtpart[c * NGT + g] = gmin.y + G1.w;
    }

    // ---- phase 2: pred-side min; 2 preds/lane, gt quarter via s_load ----
    {
        const int lane = tid & 63, wid = tid >> 6;
        const float4 P0 = pp[2*lane];            // coalesced vector loads
        const float4 P1 = pp[2*lane + 1];
        v2f px = {P0.x, P1.x};
        v2f py = {P0.y, P1.y};
        v2f pz = {P0.z, P1.z};
        v2f mn = {3.0e38f, 3.0e38f};
        const float4* __restrict__ qq = gtpack + gbase + wid * 128;  // uniform
        #pragma unroll 8
        for (int k = 0; k < 128; ++k) {
            const float4 q = qq[k];              // uniform -> s_load_dwordx4
            v2f dot = px * q.x;
            dot += py * q.y;
            dot += pz * q.z;
            v2f t = dot * -2.0f + q.w;           // g2 - 2*dot
            mn.x = fminf(mn.x, t.x);
            mn.y = fminf(mn.y, t.y);
        }
        const int pj0 = 2*lane, pj1 = 2*lane + 1;
        if (pj0 < np)
            atomicMin((int*)(predmin + poff + coff + pj0),
                      __float_as_int(mn.x + P0.w));
        if (pj1 < np)
            atomicMin((int*)(predmin + poff + coff + pj1),
                      __float_as_int(mn.y + P1.w));
    }
}

// ---------------------------------------------------------------------------
// Partial reduce + fused final (last-block pattern).
// Index space: [0,7500) gt float4 min-combine over 27 gtpart slices |
// [7500,10740) predmin | [10740,20442) edges | [20442,23682) laplace.
// Last block sums the 128 partials in fixed tree order -> deterministic.
// ---------------------------------------------------------------------------
__global__ __launch_bounds__(256) void partial_kernel(
    const float* __restrict__ pc0, const float* __restrict__ pc1, const float* __restrict__ pc2,
    const float* __restrict__ pbd0, const float* __restrict__ pbd1, const float* __restrict__ pbd2,
    const int* __restrict__ ed0, const int* __restrict__ ed1, const int* __restrict__ ed2,
    const int* __restrict__ li0, const int* __restrict__ li1, const int* __restrict__ li2,
    const float* __restrict__ gtpart, const float* __restrict__ predmin,
    float* __restrict__ partials, unsigned* __restrict__ counter,
    float* __restrict__ out)
{
    const int   NVs[3]   = {156, 618, 2466};
    const int   NEs[3]   = {462, 1848, 7392};
    const int   poffs[3] = {0, 156, 774};
    const int   eoffs[3] = {0, 462, 2310};
    const float lapc[3]  = {0.2f, 1.0f, 1.0f};
    const float* pcs[3]  = {pc0, pc1, pc2};
    const float* pbds[3] = {pbd0, pbd1, pbd2};
    const int*   eds[3]  = {ed0, ed1, ed2};
    const int*   lis[3]  = {li0, li1, li2};

    const int tid = threadIdx.x;
    const int stride = gridDim.x * 256;
    float ch = 0.f, ed = 0.f, lp = 0.f;

    for (int idx = blockIdx.x * 256 + tid; idx < 23682; idx += stride) {
        if (idx < 7500) {
            const float4* gp = (const float4*)gtpart;   // [cc*7500 + idx]
            float4 a = gp[0 * 7500 + idx];
            float4 b = gp[1 * 7500 + idx];
            float4 m0 = make_float4(fminf(a.x,b.x), fminf(a.y,b.y),
                                    fminf(a.z,b.z), fminf(a.w,b.w));
            float4 m1 = make_float4(3.0e38f, 3.0e38f, 3.0e38f, 3.0e38f);
            #pragma unroll
            for (int cc = 2; cc < 7; ++cc) {
                float4 q = gp[cc * 7500 + idx];
                m1.x = fminf(m1.x, q.x); m1.y = fminf(m1.y, q.y);
                m1.z = fminf(m1.z, q.z); m1.w = fminf(m1.w, q.w);
            }
            float4 m2 = make_float4(3.0e38f, 3.0e38f, 3.0e38f, 3.0e38f);
            #pragma unroll
            for (int cc = 7; cc < 27; ++cc) {
                float4 q = gp[cc * 7500 + idx];
                m2.x = fminf(m2.x, q.x); m2.y = fminf(m2.y, q.y);
                m2.z = fminf(m2.z, q.z); m2.w = fminf(m2.w, q.w);
            }
            float s0 = (m0.x + m1.x + m2.x) + (m0.y + m1.y + m2.y);
            float s1 = (m0.z + m1.z + m2.z) + (m0.w + m1.w + m2.w);
            ch += (s0 + s1) * (1.0f / 30000.0f);
        } else if (idx < 10740) {
            int p = idx - 7500;
            int m = (p < 156) ? 0 : (p < 774) ? 1 : 2;
            ch += predmin[p] * (1.0f / (float)NVs[m]);
        } else if (idx < 20442) {
            int e = idx - 10740;
            int m = (e < 462) ? 0 : (e < 2310) ? 1 : 2;
            int el = e - eoffs[m];
            const int* E = eds[m];
            const float* P = pcs[m];
            int a = E[2*el], b = E[2*el+1];
            float dx = P[3*a]   - P[3*b];
            float dy = P[3*a+1] - P[3*b+1];
            float dz = P[3*a+2] - P[3*b+2];
            ed += (dx*dx + dy*dy + dz*dz) * (300.0f / (float)NEs[m]);
        } else {
            int v = idx - 20442;
            int m = (v < 156) ? 0 : (v < 774) ? 1 : 2;
            int vl = v - poffs[m];
            const int* L = lis[m];
            const float* PB = pbds[m];
            const float* PC = pcs[m];
            float mvx = PB[3*vl]   - PC[3*vl];
            float mvy = PB[3*vl+1] - PC[3*vl+1];
            float mvz = PB[3*vl+2] - PC[3*vl+2];
            float sx = 0.f, sy = 0.f, sz = 0.f;
            #pragma unroll
            for (int k = 0; k < 8; ++k) {
                int nb = L[10*vl + k];
                if (nb >= 0) {
                    sx += PB[3*nb]   - PC[3*nb];
                    sy += PB[3*nb+1] - PC[3*nb+1];
                    sz += PB[3*nb+2] - PC[3*nb+2];
                }
            }
            float invdeg = 1.0f / (float)L[10*vl + 9];
            float dx = mvx - sx * invdeg;
            float dy = mvy - sy * invdeg;
            float dz = mvz - sz * invdeg;
            float t = dx*dx + dy*dy + dz*dz;
            if (m > 0) t += mvx*mvx + mvy*mvy + mvz*mvz;
            lp += t * (lapc[m] / (float)NVs[m]);
        }
    }

    __shared__ float sred[12];
    __shared__ int is_last;
    for (int off = 32; off; off >>= 1) {
        ch += __shfl_down(ch, off, 64);
        ed += __shfl_down(ed, off, 64);
        lp += __shfl_down(lp, off, 64);
    }
    const int lane = tid & 63, wid = tid >> 6;
    if (lane == 0) { sred[wid] = ch; sred[4 + wid] = ed; sred[8 + wid] = lp; }
    __syncthreads();
    if (tid == 0) {
        partials[blockIdx.x * 4 + 0] = sred[0] + sred[1] + sred[2] + sred[3];
        partials[blockIdx.x * 4 + 1] = sred[4] + sred[5] + sred[6] + sred[7];
        partials[blockIdx.x * 4 + 2] = sred[8] + sred[9] + sred[10] + sred[11];
        __threadfence();
        unsigned prev = atomicAdd(counter, 1u);
        is_last = (prev == (unsigned)(gridDim.x - 1)) ? 1 : 0;
    }
    __syncthreads();

    if (is_last) {
        __threadfence();
        float c2 = 0.f, e2 = 0.f, l2 = 0.f;
        if (tid < RB) {
            c2 = partials[4*tid]; e2 = partials[4*tid+1]; l2 = partials[4*tid+2];
        }
        for (int off = 32; off; off >>= 1) {
            c2 += __shfl_down(c2, off, 64);
            e2 += __shfl_down(e2, off, 64);
            l2 += __shfl_down(l2, off, 64);
        }
        __shared__ float s2[12];
        if (lane == 0) { s2[wid] = c2; s2[4 + wid] = e2; s2[8 + wid] = l2; }
        __syncthreads();
        if (tid == 0) {
            float C = s2[0] + s2[1];       // wids 2,3 contributed zeros
            float E = s2[4] + s2[5];
            float L = s2[8] + s2[9];
            out[0] = 100.0f * C + 0.1f * E + 0.3f * L;
            out[1] = C;
            out[2] = E;
            out[3] = L;
        }
    }
}

extern "C" void kernel_launch(void* const* d_in, const int* in_sizes, int n_in,
                              void* d_out, int out_size, void* d_ws, size_t ws_size,
                              hipStream_t stream) {
    const float* gt   = (const float*)d_in[0];
    const float* pc0  = (const float*)d_in[1];
    const float* pbd0 = (const float*)d_in[2];
    const int*   ed0  = (const int*)  d_in[3];
    const int*   li0  = (const int*)  d_in[4];
    const float* pc1  = (const float*)d_in[5];
    const float* pbd1 = (const float*)d_in[6];
    const int*   ed1  = (const int*)  d_in[7];
    const int*   li1  = (const int*)  d_in[8];
    const float* pc2  = (const float*)d_in[9];
    const float* pbd2 = (const float*)d_in[10];
    const int*   ed2  = (const int*)  d_in[11];
    const int*   li2  = (const int*)  d_in[12];

    float* ws         = (float*)d_ws;
    float4* gtpack    = (float4*)(ws + OFF_GTPACK);
    float4* predpack  = (float4*)(ws + OFF_PREDPACK);
    float* gtpart     = ws + OFF_GTPART;
    float* predmin    = ws + OFF_PREDMIN;
    float* partials   = ws + OFF_PARTIALS;
    unsigned* counter = (unsigned*)(ws + OFF_COUNTER);
    float* out        = (float*)d_out;

    pack_kernel<<<(NGTPAD + NPACK + 255) / 256, 256, 0, stream>>>(
        gt, pbd0, pbd1, pbd2, gtpack, predpack, predmin, counter);

    dim3 grid(NBLK_G, NCHUNK);
    chamfer_kernel<<<grid, 256, 0, stream>>>(gtpack, predpack, gtpart, predmin);

    partial_kernel<<<RB, 256, 0, stream>>>(pc0, pc1, pc2, pbd0, pbd1, pbd2,
                                           ed0, ed1, ed2, li0, li1, li2,
                                           gtpart, predmin, partials, counter, out);
}

// Round 14
// 45.419 us; speedup vs baseline: 1.6262x; 1.5250x over previous
//
#include <hip/hip_runtime.h>

#define NGT 30000
#define GT_TILE 512
#define NBLK_G 59            // ceil(30000/512)
#define PRANGE 64            // preds per block (R14: halved for 2x grid)
#define NCHUNK 52            // m0: 3, m1: 10, m2: 39 chunks of 64
#define NPACK 3328           // 52 * 64 chunk-padded pred slots
#define RB 128               // reduce blocks

typedef float v2f __attribute__((ext_vector_type(2)));

// ws layout (float offsets). predpack first (16B aligned at ws base).
#define OFF_PREDPACK 0              // 3328 float4 = 13312 floats
#define OFF_GTPART   13312          // 52 * 30000 = 1560000 (16B-aligned)
#define OFF_PREDMIN  1573312        // 3240
#define OFF_PARTIALS 1576552        // RB*4 = 512
#define OFF_COUNTER  1577064        // 1 uint

// ---------------------------------------------------------------------------
// Pack kernel: predpack[i] = {x,y,z,norm} (sentinel w=3e38 for pad slots);
// also inits predmin[3240] and zeroes the done-counter (no memset dispatch).
// Layout: m0 slots [0,192), m1 [192,832), m2 [832,3328).
// ---------------------------------------------------------------------------
__global__ __launch_bounds__(256) void pack_kernel(
    const float* __restrict__ pbd0,
    const float* __restrict__ pbd1,
    const float* __restrict__ pbd2,
    float4* __restrict__ predpack,
    float* __restrict__ predmin,
    unsigned* __restrict__ counter)
{
    const int i = blockIdx.x * 256 + threadIdx.x;
    if (i == 0) *counter = 0u;
    if (i < 3240) predmin[i] = __int_as_float(0x7f7f7f7f);
    if (i >= NPACK) return;
    int mesh, j, n;
    if (i < 192)      { mesh = 0; j = i;       n = 156; }
    else if (i < 832) { mesh = 1; j = i - 192; n = 618; }
    else              { mesh = 2; j = i - 832; n = 2466; }
    const float* p = (mesh == 0) ? pbd0 : (mesh == 1) ? pbd1 : pbd2;
    float4 v = make_float4(0.f, 0.f, 0.f, 3.0e38f);
    if (j < n) {
        float x = p[3*j], y = p[3*j+1], z = p[3*j+2];
        v = make_float4(x, y, z, x*x + y*y + z*z);
    }
    predpack[i] = v;
}

// ---------------------------------------------------------------------------
// Two-phase chamfer (R11 structure — best measured — with 2x grid).
// grid = (59, 52) = 3068 blocks, block = 256. LDS: sgt[512]+spred[64] (9 KB).
// R13 lesson: s_load for the PRED slice only (2 KB, K$-shared by consecutive
// blocks with same blockIdx.y); gt tile stays in LDS (8 KB/block thrashes K$).
// Phase 1: 2 gt/thread as v2f; 64 preds via wave-uniform s_load_dwordx4;
//          packed v_pk_fma (~3 VALU/pair); plain store to gtpart[c][g].
// Phase 2: 8-lane groups own 2 preds (v2f); lane s scans interleaved slice
//          sgt[k*8+s] (8 distinct 16B addrs/wave -> 32 banks, conflict-free);
//          3-level shfl_xor within group -> atomicMin predmin (int bits of
//          non-negative floats: exact, order-independent, deterministic).
// Sentinel slots carry w=3e38 so they never win a min.
// ---------------------------------------------------------------------------
__global__ __launch_bounds__(256) void chamfer_kernel(
    const float* __restrict__ gt,
    const float4* __restrict__ predpack,
    float* __restrict__ gtpart,    // [NCHUNK * NGT], write-only
    float* __restrict__ predmin)   // [3240], pre-init by pack_kernel
{
    __shared__ float4 sgt[GT_TILE];
    __shared__ float4 spred[PRANGE];

    const int tid = threadIdx.x;
    const int c = blockIdx.y;

    int mesh, cidx;
    if (c < 3)       { mesh = 0; cidx = c; }
    else if (c < 13) { mesh = 1; cidx = c - 3; }
    else             { mesh = 2; cidx = c - 13; }
    const int coff = cidx * PRANGE;
    const int n    = (mesh == 0) ? 156 : (mesh == 1) ? 618 : 2466;
    const int poff = (mesh == 0) ? 0   : (mesh == 1) ? 156 : 774;
    const int pbase = ((mesh == 0) ? 0 : (mesh == 1) ? 192 : 832) + coff;
    const int np = min(PRANGE, n - coff);

    if (tid < PRANGE) spred[tid] = predpack[pbase + tid];

    const int gbase = blockIdx.x * GT_TILE;
    float gx[2], gy[2], gz[2], g2[2];
    #pragma unroll
    for (int k = 0; k < 2; ++k) {
        const int g = gbase + k * 256 + tid;
        float x = 1e18f, y = 1e18f, z = 1e18f;   // sentinel gt: huge, finite
        if (g < NGT) { x = gt[3*g]; y = gt[3*g+1]; z = gt[3*g+2]; }
        gx[k] = x; gy[k] = y; gz[k] = z;
        g2[k] = x*x + y*y + z*z;
        sgt[k * 256 + tid] = make_float4(x, y, z, g2[k]);
    }
    __syncthreads();

    // ---- phase 1: gt-side min; uniform s_load preds + packed f32 math ----
    {
        v2f gxv = {gx[0], gx[1]};
        v2f gyv = {gy[0], gy[1]};
        v2f gzv = {gz[0], gz[1]};
        v2f gminv = {3.0e38f, 3.0e38f};
        const float4* __restrict__ pp = predpack + pbase;  // uniform base
        #pragma unroll 8
        for (int j = 0; j < PRANGE; ++j) {
            const float4 p = pp[j];              // uniform -> s_load_dwordx4
            v2f dot = gxv * p.x;
            dot += gyv * p.y;                    // v_pk_fma
            dot += gzv * p.z;
            v2f t = dot * -2.0f + p.w;           // p2 - 2*dot
            gminv.x = fminf(gminv.x, t.x);
            gminv.y = fminf(gminv.y, t.y);
        }
        const float gm0 = gminv.x + g2[0];
        const float gm1 = gminv.y + g2[1];
        int g = gbase + tid;
        if (g < NGT)       gtpart[c * NGT + g] = gm0;
        g += 256;
        if (g < NGT)       gtpart[c * NGT + g] = gm1;
    }

    // ---- phase 2: 8-lane groups x 2 preds (v2f), conflict-free scan ----
    {
        const int grp = tid >> 3;                  // 0..31 -> preds 2g,2g+1
        const int s   = tid & 7;                   // interleaved slice
        const float4 P0 = spred[2*grp+0], P1 = spred[2*grp+1];
        v2f px = {P0.x, P1.x};
        v2f py = {P0.y, P1.y};
        v2f pz = {P0.z, P1.z};
        v2f mn = {3.0e38f, 3.0e38f};
        #pragma unroll 4
        for (int k = 0; k < GT_TILE / 8; ++k) {
            const float4 q = sgt[k * 8 + s];       // 8 addrs -> banks 0..31
            v2f dot = px * q.x;
            dot += py * q.y;
            dot += pz * q.z;
            v2f t = dot * -2.0f + q.w;             // g2 - 2*dot
            mn.x = fminf(mn.x, t.x);
            mn.y = fminf(mn.y, t.y);
        }
        float mn0 = mn.x, mn1 = mn.y;
        #pragma unroll
        for (int off = 1; off < 8; off <<= 1) {
            mn0 = fminf(mn0, __shfl_xor(mn0, off, 64));
            mn1 = fminf(mn1, __shfl_xor(mn1, off, 64));
        }
        if (s == 0) {
            const int pj0 = 2*grp, pj1 = 2*grp + 1;
            if (pj0 < np)
                atomicMin((int*)(predmin + poff + coff + pj0),
                          __float_as_int(mn0 + P0.w));
            if (pj1 < np)
                atomicMin((int*)(predmin + poff + coff + pj1),
                          __float_as_int(mn1 + P1.w));
        }
    }
}

// ---------------------------------------------------------------------------
// Partial reduce + fused final (last-block pattern).
// Index space: [0,7500) gt float4 min-combine over 52 gtpart slices |
// [7500,10740) predmin | [10740,20442) edges | [20442,23682) laplace.
// Last block sums the 128 partials in fixed tree order -> deterministic.
// ---------------------------------------------------------------------------
__global__ __launch_bounds__(256) void partial_kernel(
    const float* __restrict__ pc0, const float* __restrict__ pc1, const float* __restrict__ pc2,
    const float* __restrict__ pbd0, const float* __restrict__ pbd1, const float* __restrict__ pbd2,
    const int* __restrict__ ed0, const int* __restrict__ ed1, const int* __restrict__ ed2,
    const int* __restrict__ li0, const int* __restrict__ li1, const int* __restrict__ li2,
    const float* __restrict__ gtpart, const float* __restrict__ predmin,
    float* __restrict__ partials, unsigned* __restrict__ counter,
    float* __restrict__ out)
{
    const int   NVs[3]   = {156, 618, 2466};
    const int   NEs[3]   = {462, 1848, 7392};
    const int   poffs[3] = {0, 156, 774};
    const int   eoffs[3] = {0, 462, 2310};
    const float lapc[3]  = {0.2f, 1.0f, 1.0f};
    const float* pcs[3]  = {pc0, pc1, pc2};
    const float* pbds[3] = {pbd0, pbd1, pbd2};
    const int*   eds[3]  = {ed0, ed1, ed2};
    const int*   lis[3]  = {li0, li1, li2};

    const int tid = threadIdx.x;
    const int stride = gridDim.x * 256;
    float ch = 0.f, ed = 0.f, lp = 0.f;

    for (int idx = blockIdx.x * 256 + tid; idx < 23682; idx += stride) {
        if (idx < 7500) {
            // 4 gt points per item, float4 loads (all offsets 16B-aligned)
            const float4* gp = (const float4*)gtpart;   // [cc*7500 + idx]
            float4 m0 = make_float4(3.0e38f, 3.0e38f, 3.0e38f, 3.0e38f);
            #pragma unroll
            for (int cc = 0; cc < 3; ++cc) {
                float4 q = gp[cc * 7500 + idx];
                m0.x = fminf(m0.x, q.x); m0.y = fminf(m0.y, q.y);
                m0.z = fminf(m0.z, q.z); m0.w = fminf(m0.w, q.w);
            }
            float4 m1 = make_float4(3.0e38f, 3.0e38f, 3.0e38f, 3.0e38f);
            #pragma unroll
            for (int cc = 3; cc < 13; ++cc) {
                float4 q = gp[cc * 7500 + idx];
                m1.x = fminf(m1.x, q.x); m1.y = fminf(m1.y, q.y);
                m1.z = fminf(m1.z, q.z); m1.w = fminf(m1.w, q.w);
            }
            float4 m2 = make_float4(3.0e38f, 3.0e38f, 3.0e38f, 3.0e38f);
            #pragma unroll
            for (int cc = 13; cc < 52; ++cc) {
                float4 q = gp[cc * 7500 + idx];
                m2.x = fminf(m2.x, q.x); m2.y = fminf(m2.y, q.y);
                m2.z = fminf(m2.z, q.z); m2.w = fminf(m2.w, q.w);
            }
            float s0 = (m0.x + m1.x + m2.x) + (m0.y + m1.y + m2.y);
            float s1 = (m0.z + m1.z + m2.z) + (m0.w + m1.w + m2.w);
            ch += (s0 + s1) * (1.0f / 30000.0f);
        } else if (idx < 10740) {
            int p = idx - 7500;
            int m = (p < 156) ? 0 : (p < 774) ? 1 : 2;
            ch += predmin[p] * (1.0f / (float)NVs[m]);
        } else if (idx < 20442) {
            int e = idx - 10740;
            int m = (e < 462) ? 0 : (e < 2310) ? 1 : 2;
            int el = e - eoffs[m];
            const int* E = eds[m];
            const float* P = pcs[m];
            int a = E[2*el], b = E[2*el+1];
            float dx = P[3*a]   - P[3*b];
            float dy = P[3*a+1] - P[3*b+1];
            float dz = P[3*a+2] - P[3*b+2];
            ed += (dx*dx + dy*dy + dz*dz) * (300.0f / (float)NEs[m]);
        } else {
            int v = idx - 20442;
            int m = (v < 156) ? 0 : (v < 774) ? 1 : 2;
            int vl = v - poffs[m];
            const int* L = lis[m];
            const float* PB = pbds[m];
            const float* PC = pcs[m];
            float mvx = PB[3*vl]   - PC[3*vl];
            float mvy = PB[3*vl+1] - PC[3*vl+1];
            float mvz = PB[3*vl+2] - PC[3*vl+2];
            float sx = 0.f, sy = 0.f, sz = 0.f;
            #pragma unroll
            for (int k = 0; k < 8; ++k) {
                int nb = L[10*vl + k];
                if (nb >= 0) {
                    sx += PB[3*nb]   - PC[3*nb];
                    sy += PB[3*nb+1] - PC[3*nb+1];
                    sz += PB[3*nb+2] - PC[3*nb+2];
                }
            }
            float invdeg = 1.0f / (float)L[10*vl + 9];
            float dx = mvx - sx * invdeg;
            float dy = mvy - sy * invdeg;
            float dz = mvz - sz * invdeg;
            float t = dx*dx + dy*dy + dz*dz;
            if (m > 0) t += mvx*mvx + mvy*mvy + mvz*mvz;
            lp += t * (lapc[m] / (float)NVs[m]);
        }
    }

    __shared__ float sred[12];
    __shared__ int is_last;
    for (int off = 32; off; off >>= 1) {
        ch += __shfl_down(ch, off, 64);
        ed += __shfl_down(ed, off, 64);
        lp += __shfl_down(lp, off, 64);
    }
    const int lane = tid & 63, wid = tid >> 6;
    if (lane == 0) { sred[wid] = ch; sred[4 + wid] = ed; sred[8 + wid] = lp; }
    __syncthreads();
    if (tid == 0) {
        partials[blockIdx.x * 4 + 0] = sred[0] + sred[1] + sred[2] + sred[3];
        partials[blockIdx.x * 4 + 1] = sred[4] + sred[5] + sred[6] + sred[7];
        partials[blockIdx.x * 4 + 2] = sred[8] + sred[9] + sred[10] + sred[11];
        __threadfence();
        unsigned prev = atomicAdd(counter, 1u);
        is_last = (prev == (unsigned)(gridDim.x - 1)) ? 1 : 0;
    }
    __syncthreads();

    if (is_last) {
        __threadfence();
        float c2 = 0.f, e2 = 0.f, l2 = 0.f;
        if (tid < RB) {
            c2 = partials[4*tid]; e2 = partials[4*tid+1]; l2 = partials[4*tid+2];
        }
        for (int off = 32; off; off >>= 1) {
            c2 += __shfl_down(c2, off, 64);
            e2 += __shfl_down(e2, off, 64);
            l2 += __shfl_down(l2, off, 64);
        }
        __shared__ float s2[12];
        if (lane == 0) { s2[wid] = c2; s2[4 + wid] = e2; s2[8 + wid] = l2; }
        __syncthreads();
        if (tid == 0) {
            float C = s2[0] + s2[1];       // wids 2,3 contributed zeros
            float E = s2[4] + s2[5];
            float L = s2[8] + s2[9];
            out[0] = 100.0f * C + 0.1f * E + 0.3f * L;
            out[1] = C;
            out[2] = E;
            out[3] = L;
        }
    }
}

extern "C" void kernel_launch(void* const* d_in, const int* in_sizes, int n_in,
                              void* d_out, int out_size, void* d_ws, size_t ws_size,
                              hipStream_t stream) {
    const float* gt   = (const float*)d_in[0];
    const float* pc0  = (const float*)d_in[1];
    const float* pbd0 = (const float*)d_in[2];
    const int*   ed0  = (const int*)  d_in[3];
    const int*   li0  = (const int*)  d_in[4];
    const float* pc1  = (const float*)d_in[5];
    const float* pbd1 = (const float*)d_in[6];
    const int*   ed1  = (const int*)  d_in[7];
    const int*   li1  = (const int*)  d_in[8];
    const float* pc2  = (const float*)d_in[9];
    const float* pbd2 = (const float*)d_in[10];
    const int*   ed2  = (const int*)  d_in[11];
    const int*   li2  = (const int*)  d_in[12];

    float* ws         = (float*)d_ws;
    float4* predpack  = (float4*)(ws + OFF_PREDPACK);
    float* gtpart     = ws + OFF_GTPART;
    float* predmin    = ws + OFF_PREDMIN;
    float* partials   = ws + OFF_PARTIALS;
    unsigned* counter = (unsigned*)(ws + OFF_COUNTER);
    float* out        = (float*)d_out;

    pack_kernel<<<(NPACK + 255) / 256, 256, 0, stream>>>(
        pbd0, pbd1, pbd2, predpack, predmin, counter);

    dim3 grid(NBLK_G, NCHUNK);
    chamfer_kernel<<<grid, 256, 0, stream>>>(gt, predpack, gtpart, predmin);

    partial_kernel<<<RB, 256, 0, stream>>>(pc0, pc1, pc2, pbd0, pbd1, pbd2,
                                           ed0, ed1, ed2, li0, li1, li2,
                                           gtpart, predmin, partials, counter, out);
}